// Round 1
// 161.469 us; speedup vs baseline: 1.0487x; 1.0487x over previous
//
#include <hip/hip_runtime.h>

#define B_SZ   512
#define VFD    4096
#define HIDD   2048
#define EMBD   300
#define NLAB   2000
#define NPAD   320

#define G1_SPLIT 4          // gemm1 k-chunks: K=4096 -> 1024 each
#define G2_SPLIT 8          // gemm2 k-chunks: K=2048 -> 256 each

typedef __attribute__((ext_vector_type(8))) short short8x;
typedef __attribute__((ext_vector_type(4))) float f32x4;
typedef __attribute__((ext_vector_type(8))) unsigned short ushort8;
typedef __attribute__((ext_vector_type(4))) unsigned short ushort4x;
typedef __attribute__((ext_vector_type(2))) _Float16 h2;

typedef const __attribute__((address_space(1))) unsigned int* gas_t;
typedef __attribute__((address_space(3))) unsigned int* las_t;

__device__ inline unsigned short f2bf(float x) {
    unsigned u = __float_as_uint(x);
    u += 0x7FFF + ((u >> 16) & 1);          // round-to-nearest-even
    return (unsigned short)(u >> 16);
}

__device__ inline unsigned short f2hneg(float x) {
    _Float16 h = (_Float16)(-x);            // v_cvt_f16_f32 (RNE) with neg
    return __builtin_bit_cast(unsigned short, h);
}

// ---------------------------------------------------------------------------
// Fused prep (grid-range dispatch):
//   [0,1024):       Xb = bf16(relu(vfs))
//   [1024,3072):    W1T[n][k] = bf16(W1[k][n])  (pair-packed transpose v2)
//   [3072,3232):    W2T[n][k] = bf16(W2[k][n]), n>=300 zero-padded
//   [3232,3525):    Gh = f16(-G)  (pre-negated for pk_add in scores)
// ---------------------------------------------------------------------------
__global__ __launch_bounds__(256) void prep_kernel(
    const float* __restrict__ vfs, unsigned short* __restrict__ Xb,
    const float* __restrict__ W1, unsigned short* __restrict__ W1T,
    const float* __restrict__ W2, unsigned short* __restrict__ W2T,
    const float* __restrict__ G,  unsigned short* __restrict__ Gh)
{
    __shared__ unsigned int Lds[64][34];    // [n][kpair], stride 34 (b64-aligned)
    const int tid = threadIdx.x;
    const int blk = blockIdx.x;

    if (blk < 1024) {                       // Xb = bf16(relu(vfs))
        const int i = (blk * 256 + tid) * 8;
        float4 a = *(const float4*)&vfs[i];
        float4 b = *(const float4*)&vfs[i + 4];
        ushort8 o;
        o[0] = f2bf(fmaxf(a.x, 0.f)); o[1] = f2bf(fmaxf(a.y, 0.f));
        o[2] = f2bf(fmaxf(a.z, 0.f)); o[3] = f2bf(fmaxf(a.w, 0.f));
        o[4] = f2bf(fmaxf(b.x, 0.f)); o[5] = f2bf(fmaxf(b.y, 0.f));
        o[6] = f2bf(fmaxf(b.z, 0.f)); o[7] = f2bf(fmaxf(b.w, 0.f));
        *(ushort8*)&Xb[i] = o;
        return;
    }
    if (blk >= 3232) {                      // Gh = f16(-G), 8 elems/thread
        const int i = ((blk - 3232) * 256 + tid) * 8;
        if (i + 8 <= NLAB * EMBD) {
            float4 a = *(const float4*)&G[i];
            float4 b = *(const float4*)&G[i + 4];
            ushort8 o;
            o[0] = f2hneg(a.x); o[1] = f2hneg(a.y);
            o[2] = f2hneg(a.z); o[3] = f2hneg(a.w);
            o[4] = f2hneg(b.x); o[5] = f2hneg(b.y);
            o[6] = f2hneg(b.z); o[7] = f2hneg(b.w);
            *(ushort8*)&Gh[i] = o;
        }
        return;
    }

    const float* in; unsigned short* out; int N, ldK, bx, by;
    if (blk < 3072) {                       // W1: K=4096, N=2048, tiles (32,64)
        const int b = blk - 1024;
        in = W1; out = W1T; N = HIDD; ldK = VFD; bx = b & 31; by = b >> 5;
    } else {                                // W2: K=2048, N=300->320, tiles (5,32)
        const int b = blk - 3072;
        in = W2; out = W2T; N = EMBD; ldK = HIDD; bx = b % 5; by = b / 5;
    }
    const int n0 = bx * 64, k0 = by * 64;

    // phase 1: 512 slots (kpair 0..31 x nquad 0..15), 2 per thread
    #pragma unroll
    for (int i = 0; i < 2; ++i) {
        const int s = tid + 256 * i;
        const int kp = s >> 4, nq = s & 15;
        const int n = n0 + nq * 4;
        float4 v0 = {0.f,0.f,0.f,0.f}, v1 = {0.f,0.f,0.f,0.f};
        if (n < N) {
            v0 = *(const float4*)&in[(size_t)(k0 + 2 * kp)     * N + n];
            v1 = *(const float4*)&in[(size_t)(k0 + 2 * kp + 1) * N + n];
        }
        Lds[nq*4+0][kp] = (unsigned)f2bf(v0.x) | ((unsigned)f2bf(v1.x) << 16);
        Lds[nq*4+1][kp] = (unsigned)f2bf(v0.y) | ((unsigned)f2bf(v1.y) << 16);
        Lds[nq*4+2][kp] = (unsigned)f2bf(v0.z) | ((unsigned)f2bf(v1.z) << 16);
        Lds[nq*4+3][kp] = (unsigned)f2bf(v0.w) | ((unsigned)f2bf(v1.w) << 16);
    }
    __syncthreads();

    // phase 2: 512 chunks (n 0..63 x k-octet 0..7), 2 per thread
    #pragma unroll
    for (int i = 0; i < 2; ++i) {
        const int c = tid + 256 * i;
        const int n = c >> 3, oct = c & 7;
        uint2 lo = *(uint2*)&Lds[n][oct * 4];
        uint2 hi = *(uint2*)&Lds[n][oct * 4 + 2];
        uint4 v = make_uint4(lo.x, lo.y, hi.x, hi.y);
        *(uint4*)&out[(size_t)(n0 + n) * ldK + k0 + oct * 8] = v;
    }
}

// ---------------------------------------------------------------------------
// GEMM1: Hpart[z][512][2048] = Xb @ W1T^T over k-chunk z.
// Block 64m x 128n, BK=64 (16 iters). 4 waves, wave = 32m x 64n.
// LDS dbuf 48 KB. Grid (16,8,4).
// ---------------------------------------------------------------------------
__global__ __launch_bounds__(256) void gemm1_kernel(
    const unsigned short* __restrict__ A,
    const unsigned short* __restrict__ Bt,
    float* __restrict__ Cpart)
{
    __shared__ unsigned short As[2][4096];   // 8 oct x 64 rows  (8 KB each)
    __shared__ unsigned short Bs[2][8192];   // 8 oct x 128 rows (16 KB each)

    const int tid = threadIdx.x;
    const int m0 = blockIdx.y * 64, n0 = blockIdx.x * 128;
    const int kbase = blockIdx.z * (VFD / G1_SPLIT);     // 1024

    const unsigned short* ga = A + (size_t)(m0 + (tid & 63)) * VFD + kbase + (tid >> 6) * 8;
    const unsigned short* gb = Bt + (size_t)(n0 + (tid & 127)) * VFD + kbase + (tid >> 7) * 8;

    const int lane = tid & 63;
    const int wave = tid >> 6;
    const int wm = (wave & 1) * 32;
    const int wn = (wave >> 1) * 64;
    const int q = lane >> 4, l15 = lane & 15;

    f32x4 acc[2][4];
    #pragma unroll
    for (int r = 0; r < 2; ++r)
        #pragma unroll
        for (int c = 0; c < 4; ++c) acc[r][c] = (f32x4){0.f,0.f,0.f,0.f};

    #pragma unroll
    for (int i = 0; i < 2; ++i)
        __builtin_amdgcn_global_load_lds((gas_t)(const void*)(ga + i * 32),
                                         (las_t)(void*)&As[0][(tid + 256 * i) * 8], 16, 0, 0);
    #pragma unroll
    for (int i = 0; i < 4; ++i)
        __builtin_amdgcn_global_load_lds((gas_t)(const void*)(gb + i * 16),
                                         (las_t)(void*)&Bs[0][(tid + 256 * i) * 8], 16, 0, 0);

    const int iters = (VFD / G1_SPLIT) / 64;             // 16
    for (int t = 0; t < iters; ++t) {
        const int cur = t & 1, nxt = cur ^ 1;
        __syncthreads();            // vmcnt drain: tile t present; buf[nxt] free

        if (t + 1 < iters) {
            const int ko = (t + 1) * 64;
            #pragma unroll
            for (int i = 0; i < 2; ++i)
                __builtin_amdgcn_global_load_lds((gas_t)(const void*)(ga + ko + i * 32),
                                                 (las_t)(void*)&As[nxt][(tid + 256 * i) * 8], 16, 0, 0);
            #pragma unroll
            for (int i = 0; i < 4; ++i)
                __builtin_amdgcn_global_load_lds((gas_t)(const void*)(gb + ko + i * 16),
                                                 (las_t)(void*)&Bs[nxt][(tid + 256 * i) * 8], 16, 0, 0);
        }

        #pragma unroll
        for (int kk = 0; kk < 2; ++kk) {
            const int oct = kk * 4 + q;
            short8x a0 = *(short8x*)&As[cur][(oct * 64 + wm +      l15) * 8];
            short8x a1 = *(short8x*)&As[cur][(oct * 64 + wm + 16 + l15) * 8];
            #pragma unroll
            for (int c = 0; c < 4; ++c) {
                short8x b = *(short8x*)&Bs[cur][(oct * 128 + wn + c * 16 + l15) * 8];
                acc[0][c] = __builtin_amdgcn_mfma_f32_16x16x32_bf16(a0, b, acc[0][c], 0, 0, 0);
                acc[1][c] = __builtin_amdgcn_mfma_f32_16x16x32_bf16(a1, b, acc[1][c], 0, 0, 0);
            }
        }
    }

    float* Cz = Cpart + (size_t)blockIdx.z * B_SZ * HIDD;
    #pragma unroll
    for (int r = 0; r < 2; ++r) {
        #pragma unroll
        for (int g = 0; g < 4; ++g) {
            const int rr = m0 + wm + r * 16 + q * 4 + g;
            #pragma unroll
            for (int c = 0; c < 4; ++c)
                Cz[(size_t)rr * HIDD + n0 + wn + c * 16 + l15] = acc[r][c][g];
        }
    }
}

// ---------------------------------------------------------------------------
// GEMM2: Epart[z] = Hb @ W2T^T over k-chunk z. BM=BN=64, BK=64 (4 iters).
// 4 waves of 32x32. Grid (5, 8, G2_SPLIT).
// ---------------------------------------------------------------------------
template<int LDA, int LDB, int LDC, int KCHUNK>
__global__ __launch_bounds__(256) void gemm_bf16_kernel(
    const unsigned short* __restrict__ A,
    const unsigned short* __restrict__ Bt,
    float* __restrict__ Cpart, int M)
{
    __shared__ unsigned short As[2][4096];   // 8 oct x 64 rows
    __shared__ unsigned short Bs[2][4096];

    const int tid = threadIdx.x;
    const int m0 = blockIdx.y * 64, n0 = blockIdx.x * 64;
    const int kbase = blockIdx.z * KCHUNK;

    const unsigned short* ga = A  + (size_t)(m0 + (tid & 63)) * LDA + kbase + (tid >> 6) * 8;
    const unsigned short* gb = Bt + (size_t)(n0 + (tid & 63)) * LDB + kbase + (tid >> 6) * 8;

    const int lane = tid & 63;
    const int wave = tid >> 6;
    const int wm = (wave & 1) * 32;
    const int wn = (wave >> 1) * 32;
    const int q = lane >> 4, l15 = lane & 15;

    f32x4 acc00 = {0.f,0.f,0.f,0.f}, acc01 = {0.f,0.f,0.f,0.f};
    f32x4 acc10 = {0.f,0.f,0.f,0.f}, acc11 = {0.f,0.f,0.f,0.f};

    #pragma unroll
    for (int i = 0; i < 2; ++i) {
        __builtin_amdgcn_global_load_lds((gas_t)(const void*)(ga + i * 32),
                                         (las_t)(void*)&As[0][(tid + 256 * i) * 8], 16, 0, 0);
        __builtin_amdgcn_global_load_lds((gas_t)(const void*)(gb + i * 32),
                                         (las_t)(void*)&Bs[0][(tid + 256 * i) * 8], 16, 0, 0);
    }

    const int iters = KCHUNK / 64;
    for (int t = 0; t < iters; ++t) {
        const int cur = t & 1, nxt = cur ^ 1;
        __syncthreads();

        if (t + 1 < iters) {
            const int ko = (t + 1) * 64;
            #pragma unroll
            for (int i = 0; i < 2; ++i) {
                __builtin_amdgcn_global_load_lds((gas_t)(const void*)(ga + ko + i * 32),
                                                 (las_t)(void*)&As[nxt][(tid + 256 * i) * 8], 16, 0, 0);
                __builtin_amdgcn_global_load_lds((gas_t)(const void*)(gb + ko + i * 32),
                                                 (las_t)(void*)&Bs[nxt][(tid + 256 * i) * 8], 16, 0, 0);
            }
        }

        #pragma unroll
        for (int kk = 0; kk < 2; ++kk) {
            const int oct = kk * 4 + q;
            short8x a0 = *(short8x*)&As[cur][(oct * 64 + wm +      l15) * 8];
            short8x a1 = *(short8x*)&As[cur][(oct * 64 + wm + 16 + l15) * 8];
            short8x b0 = *(short8x*)&Bs[cur][(oct * 64 + wn +      l15) * 8];
            short8x b1 = *(short8x*)&Bs[cur][(oct * 64 + wn + 16 + l15) * 8];
            acc00 = __builtin_amdgcn_mfma_f32_16x16x32_bf16(a0, b0, acc00, 0, 0, 0);
            acc01 = __builtin_amdgcn_mfma_f32_16x16x32_bf16(a0, b1, acc01, 0, 0, 0);
            acc10 = __builtin_amdgcn_mfma_f32_16x16x32_bf16(a1, b0, acc10, 0, 0, 0);
            acc11 = __builtin_amdgcn_mfma_f32_16x16x32_bf16(a1, b1, acc11, 0, 0, 0);
        }
    }

    float* Cz = Cpart + (size_t)blockIdx.z * M * LDC;
    #pragma unroll
    for (int r = 0; r < 4; ++r) {
        const int rr = m0 + wm + q * 4 + r;
        const int cc = n0 + wn + l15;
        Cz[(size_t)rr * LDC + cc]             = acc00[r];
        Cz[(size_t)rr * LDC + cc + 16]        = acc01[r];
        Cz[(size_t)(rr + 16) * LDC + cc]      = acc10[r];
        Cz[(size_t)(rr + 16) * LDC + cc + 16] = acc11[r];
    }
}

// ---------------------------------------------------------------------------
// Hb = bf16(relu(sum_z Hpart[z] + b1)), 4 elems/thread. Grid 1024.
// ---------------------------------------------------------------------------
__global__ __launch_bounds__(256) void reduce_h_kernel(
    const float* __restrict__ Hpart, const float* __restrict__ b1,
    unsigned short* __restrict__ Hb)
{
    const int i = (blockIdx.x * 256 + threadIdx.x) * 4;
    const int col = i & (HIDD - 1);
    float4 s = *(const float4*)&b1[col];
    #pragma unroll
    for (int z = 0; z < G1_SPLIT; ++z) {
        float4 p = *(const float4*)&Hpart[(size_t)z * B_SZ * HIDD + i];
        s.x += p.x; s.y += p.y; s.z += p.z; s.w += p.w;
    }
    ushort4x o;
    o[0] = f2bf(fmaxf(s.x, 0.f));
    o[1] = f2bf(fmaxf(s.y, 0.f));
    o[2] = f2bf(fmaxf(s.z, 0.f));
    o[3] = f2bf(fmaxf(s.w, 0.f));
    *(ushort4x*)&Hb[i] = o;
}

// ---------------------------------------------------------------------------
// E[m][n] = sum_z Epart[z][m][n] + b2[n], n < 300. Also emits Eh = f16(E)
// for the scores kernel. Grid 600.
// ---------------------------------------------------------------------------
__global__ __launch_bounds__(256) void reduce_e_kernel(
    const float* __restrict__ Epart, const float* __restrict__ b2,
    float* __restrict__ E, unsigned short* __restrict__ Eh)
{
    const int gid = blockIdx.x * 256 + threadIdx.x;
    if (gid >= B_SZ * EMBD) return;
    const int m = gid / EMBD, n = gid - m * EMBD;
    float v = b2[n];
    #pragma unroll
    for (int z = 0; z < G2_SPLIT; ++z)
        v += Epart[(size_t)z * B_SZ * NPAD + m * NPAD + n];
    E[gid] = v;
    Eh[gid] = __builtin_bit_cast(unsigned short, (_Float16)v);
}

// ---------------------------------------------------------------------------
// Scores: direct-store, packed f16. score[b][n] = -sum_d relu(e-g)^2.
// Tile 32 b x 64 n, 256 threads (4 waves), thread = 2 rows x 4 labels.
// Full 300-d reduction per block -> no atomics, no pre-zero.
// Inner op: v_pk_add_f16 (G pre-negated) + v_pk_max_f16 + v_dot2_f32_f16
// = 3 VALU / 2 elements with f32 accumulation. Grid (32,16) = 512 blocks.
// LDS G-tile stride 44 f16 (88 B) -> 16 rows on 16 distinct banks (b64 reads).
// ---------------------------------------------------------------------------
__global__ __launch_bounds__(256) void scores_kernel(
    const unsigned short* __restrict__ Eh,
    const unsigned short* __restrict__ Gh,
    float* __restrict__ scores)
{
    __shared__ unsigned short Gs[64][44];

    const int tid = threadIdx.x;
    const int tx = tid & 15, ty = tid >> 4;              // ty 0..15
    const int n0 = blockIdx.x * 64, b0 = blockIdx.y * 32;

    const h2 hz = {(_Float16)0.0f, (_Float16)0.0f};
    float acc[2][4] = {};

    for (int d0 = 0; d0 < NPAD; d0 += 40) {
        __syncthreads();
        // stage -G chunk: 64 rows x 40 dims f16 (640 uint2 slots)
        #pragma unroll
        for (int i = 0; i < 3; ++i) {
            const int s = tid + 256 * i;
            if (s < 640) {
                const int row = s / 10, qd = (s - row * 10) * 4;
                const int n = n0 + row, d = d0 + qd;
                uint2 v = make_uint2(0u, 0u);
                if (n < NLAB && d < EMBD) v = *(const uint2*)&Gh[(size_t)n * EMBD + d];
                *(uint2*)&Gs[row][qd] = v;
            }
        }
        __syncthreads();

        #pragma unroll
        for (int d = 0; d < 40; d += 4) {
            const int dd = d0 + d;
            h2 e0[2], e1[2];
            #pragma unroll
            for (int r = 0; r < 2; ++r) {
                uint2 ev = make_uint2(0u, 0u);
                if (dd < EMBD)
                    ev = *(const uint2*)&Eh[(size_t)(b0 + ty * 2 + r) * EMBD + dd];
                e0[r] = __builtin_bit_cast(h2, ev.x);
                e1[r] = __builtin_bit_cast(h2, ev.y);
            }
            #pragma unroll
            for (int c = 0; c < 4; ++c) {
                uint2 gv = *(const uint2*)&Gs[tx + 16 * c][d];
                const h2 g0 = __builtin_bit_cast(h2, gv.x);
                const h2 g1 = __builtin_bit_cast(h2, gv.y);
                #pragma unroll
                for (int r = 0; r < 2; ++r) {
                    h2 s0 = e0[r] + g0;                 // e - g (g pre-negated)
                    h2 s1 = e1[r] + g1;
                    s0 = __builtin_elementwise_max(s0, hz);
                    s1 = __builtin_elementwise_max(s1, hz);
                    acc[r][c] = __builtin_amdgcn_fdot2(s0, s0, acc[r][c], false);
                    acc[r][c] = __builtin_amdgcn_fdot2(s1, s1, acc[r][c], false);
                }
            }
        }
    }

    #pragma unroll
    for (int r = 0; r < 2; ++r) {
        const int b = b0 + ty * 2 + r;
        #pragma unroll
        for (int c = 0; c < 4; ++c) {
            const int n = n0 + tx + 16 * c;
            if (n < NLAB) scores[(size_t)b * NLAB + n] = -acc[r][c];
        }
    }
}

// ---------------------------------------------------------------------------
extern "C" void kernel_launch(void* const* d_in, const int* in_sizes, int n_in,
                              void* d_out, int out_size, void* d_ws, size_t ws_size,
                              hipStream_t stream)
{
    const float* vfs = (const float*)d_in[0];   // [512,4096]
    const float* W1  = (const float*)d_in[1];   // [4096,2048]
    const float* b1  = (const float*)d_in[2];   // [2048]
    const float* W2  = (const float*)d_in[3];   // [2048,300]
    const float* b2  = (const float*)d_in[4];   // [300]
    const float* G   = (const float*)d_in[5];   // [2000,300]

    float* out    = (float*)d_out;
    float* scores = out;                        // [512*2000]
    float* E      = out + (size_t)B_SZ * NLAB;  // [512*300]

    // workspace layout (bytes): ~47.9 MB used
    char* ws = (char*)d_ws;
    unsigned short* Xb  = (unsigned short*)(ws);             //  4 MB   [512][4096]
    unsigned short* W1T = (unsigned short*)(ws + 4194304);   // 16 MB   [2048][4096]
    unsigned short* W2T = (unsigned short*)(ws + 20971520);  // 1.25 MB [320][2048]
    unsigned short* Hb  = (unsigned short*)(ws + 22282240);  //  2 MB   [512][2048]
    float*          Hpart = (float*)(ws + 24379392);         // 16 MB   [4][512][2048]
    float*          Epart = (float*)(ws + 41156608);         // 5.25 MB [8][512][320]
    unsigned short* Gh  = (unsigned short*)(ws + 46399488);  // 1.2 MB  [2000][300] f16 (-G)
    unsigned short* Eh  = (unsigned short*)(ws + 47599488);  // 0.3 MB  [512][300]  f16

    // prep: Xb conv (1024) + W1T (2048) + W2T (160) + Gh conv (293)
    prep_kernel<<<3525, 256, 0, stream>>>(vfs, Xb, W1, W1T, W2, W2T, G, Gh);

    // GEMM1: 64x128 tile, BK=64, grid (16,8,4) = 512 blocks
    gemm1_kernel<<<dim3(16, 8, G1_SPLIT), 256, 0, stream>>>(Xb, W1T, Hpart);
    reduce_h_kernel<<<1024, 256, 0, stream>>>(Hpart, b1, Hb);

    // GEMM2: [512,320] = Hb[512,2048] @ W2T^T, BK=64, split-K 8 -> 320 blocks
    gemm_bf16_kernel<HIDD, HIDD, NPAD, HIDD / G2_SPLIT>
        <<<dim3(5, 8, G2_SPLIT), 256, 0, stream>>>(Hb, W2T, Epart, B_SZ);
    reduce_e_kernel<<<600, 256, 0, stream>>>(Epart, b2, E, Eh);

    // scores: packed-f16 direct store, grid (32,16) = 512 blocks
    scores_kernel<<<dim3(32, 16), 256, 0, stream>>>(Eh, Gh, scores);
}